// Round 3
// baseline (546.990 us; speedup 1.0000x reference)
//
#include <hip/hip_runtime.h>

#define N_ 512
#define NPOS (N_*N_)   // 262144
#define CD 128         // C == CZ == 128

typedef unsigned short ushort_t;
typedef unsigned int   uint_t;
typedef __bf16 bf16_t;
typedef bf16_t  bf16x8 __attribute__((ext_vector_type(8)));
typedef float   f32x4  __attribute__((ext_vector_type(4)));
typedef unsigned short u16x4 __attribute__((ext_vector_type(4)));
typedef uint_t  u32x4 __attribute__((ext_vector_type(4)));

__device__ __forceinline__ float bf2f(ushort_t h) {
  union { uint_t u; float f; } v; v.u = ((uint_t)h) << 16; return v.f;
}
__device__ __forceinline__ ushort_t f2bf(float f) {
  union { float f; uint_t u; } v; v.f = f;
  uint_t u = v.u;
  return (ushort_t)((u + 0x7FFFu + ((u >> 16) & 1u)) >> 16);
}
__device__ __forceinline__ float sigm(float x) { return 1.0f / (1.0f + __expf(-x)); }

// ---------------- weight transposes (f32 -> bf16): wT[m][c][k] = W_m[k][c] ----------------
__global__ void k_tw(const float* s0, const float* s1, const float* s2,
                     const float* s3, const float* s4, const float* s5,
                     ushort_t* dst) {
  const float* s;
  switch (blockIdx.x) {
    case 0: s = s0; break; case 1: s = s1; break; case 2: s = s2; break;
    case 3: s = s3; break; case 4: s = s4; break; default: s = s5; break;
  }
  ushort_t* d = dst + blockIdx.x * CD * CD;
  for (int idx = threadIdx.x; idx < CD * CD; idx += 256) {
    int c = idx >> 7, k = idx & 127;
    d[idx] = f2bf(s[k * CD + c]);
  }
}

// ---------------- LN1 (f32 in, bf16 out): 16 lanes per row, f32x4 loads ----------------
__global__ void k_ln1(const float* __restrict__ x, const float* __restrict__ gma,
                      const float* __restrict__ bta, ushort_t* __restrict__ z) {
  const int tid  = threadIdx.x;
  const int l15  = tid & 15;
  const int row  = blockIdx.x * 16 + (tid >> 4);
  const float4* src = (const float4*)(x + (size_t)row * CD + l15 * 8);
  float4 v0 = src[0], v1 = src[1];
  float s = ((v0.x + v0.y) + (v0.z + v0.w)) + ((v1.x + v1.y) + (v1.z + v1.w));
  float q = ((v0.x*v0.x + v0.y*v0.y) + (v0.z*v0.z + v0.w*v0.w))
          + ((v1.x*v1.x + v1.y*v1.y) + (v1.z*v1.z + v1.w*v1.w));
  #pragma unroll
  for (int o = 1; o < 16; o <<= 1) { s += __shfl_xor(s, o, 64); q += __shfl_xor(q, o, 64); }
  float mu = s * (1.0f / 128.0f);
  float rs = rsqrtf(q * (1.0f / 128.0f) - mu * mu + 1e-5f);
  const float4* gp = (const float4*)(gma + l15 * 8);
  const float4* bp = (const float4*)(bta + l15 * 8);
  float4 g0 = gp[0], g1v = gp[1], b0 = bp[0], b1v = bp[1];
  uint_t w0 = (uint_t)f2bf((v0.x-mu)*rs*g0.x +b0.x ) | ((uint_t)f2bf((v0.y-mu)*rs*g0.y +b0.y ) << 16);
  uint_t w1 = (uint_t)f2bf((v0.z-mu)*rs*g0.z +b0.z ) | ((uint_t)f2bf((v0.w-mu)*rs*g0.w +b0.w ) << 16);
  uint_t w2 = (uint_t)f2bf((v1.x-mu)*rs*g1v.x+b1v.x) | ((uint_t)f2bf((v1.y-mu)*rs*g1v.y+b1v.y) << 16);
  uint_t w3 = (uint_t)f2bf((v1.z-mu)*rs*g1v.z+b1v.z) | ((uint_t)f2bf((v1.w-mu)*rs*g1v.w+b1v.w) << 16);
  u32x4 pk = {w0, w1, w2, w3};
  *(u32x4*)(z + (size_t)row * CD + l15 * 8) = pk;
}

// ---------------- projections a,b: weights persistent in registers, z pipelined ----------------
// 512 blocks x 4 waves, 4 pos-tiles each (2 blocks/CU). Wave w owns couts [32w,32w+32) of the
// 4 a/b weight matrices (128 VGPR). z reg-prefetched one tile ahead -> swizzled LDS ->
// pure ds_read+MFMA. Outputs via padded LDS transpose buffer -> full-line stores.
__global__ __launch_bounds__(256, 1)
void k_proj(const ushort_t* __restrict__ z, const ushort_t* __restrict__ wT,
            ushort_t* __restrict__ aT, ushort_t* __restrict__ bT) {
  __shared__ ushort_t zl[128 * 128];   // 32KB, XOR-swizzled 16B units
  __shared__ ushort_t tb[128][136];    // 34KB transpose buffer (272B rows)
  const int tid = threadIdx.x;
  const int lane = tid & 63, w = tid >> 6;
  const int qd = lane >> 4, l15 = lane & 15;

  // persistent weight fragments: wf[m][i][kk] row = 32w+i*16+l15, col = kk*32+qd*8
  bf16x8 wf[4][2][4];
  #pragma unroll
  for (int m = 0; m < 4; ++m)
    #pragma unroll
    for (int i = 0; i < 2; ++i)
      #pragma unroll
      for (int kk = 0; kk < 4; ++kk)
        wf[m][i][kk] = *(const bf16x8*)(wT + m * CD * CD + (w * 32 + i * 16 + l15) * CD + kk * 32 + qd * 8);

  const int TILES = 4;
  const int base = blockIdx.x * TILES;

  u32x4 st[8];
  { // prologue: prefetch tile 0 into registers
    const u32x4* src = (const u32x4*)(z + (size_t)base * 128 * CD);
    #pragma unroll
    for (int i = 0; i < 8; ++i) st[i] = src[tid + i * 256];
  }

  for (int t = 0; t < TILES; ++t) {
    const int pos0 = (base + t) * 128;
    __syncthreads();                       // prev tile's zl readers done
    { // staged regs -> swizzled zl
      u32x4* dst = (u32x4*)zl;
      #pragma unroll
      for (int i = 0; i < 8; ++i) {
        int u = tid + i * 256, row = u >> 4;
        dst[(u & ~15) | ((u & 15) ^ (row & 7))] = st[i];
      }
    }
    __syncthreads();                       // zl ready for all waves
    if (t + 1 < TILES) {                   // prefetch next tile (hidden under compute)
      const u32x4* src = (const u32x4*)(z + (size_t)(base + t + 1) * 128 * CD);
      #pragma unroll
      for (int i = 0; i < 8; ++i) st[i] = src[tid + i * 256];
    }

    #pragma unroll
    for (int ab = 0; ab < 2; ++ab) {
      f32x4 ag[2][8] = {}; f32x4 av[2][8] = {};
      #pragma unroll
      for (int kk = 0; kk < 4; ++kk) {
        bf16x8 zf[8];
        #pragma unroll
        for (int j = 0; j < 8; ++j) {
          int row = j * 16 + l15, kq = kk * 4 + qd;
          zf[j] = ((const bf16x8*)zl)[(row << 4) | (kq ^ (row & 7))];
        }
        #pragma unroll
        for (int j = 0; j < 8; ++j)
          #pragma unroll
          for (int i = 0; i < 2; ++i) {
            ag[i][j] = __builtin_amdgcn_mfma_f32_16x16x32_bf16(wf[ab * 2][i][kk],     zf[j], ag[i][j], 0, 0, 0);
            av[i][j] = __builtin_amdgcn_mfma_f32_16x16x32_bf16(wf[ab * 2 + 1][i][kk], zf[j], av[i][j], 0, 0, 0);
          }
      }
      // epilogue: gate, transpose via tb, full-line stores
      #pragma unroll
      for (int i = 0; i < 2; ++i)
        #pragma unroll
        for (int j = 0; j < 8; ++j)
          #pragma unroll
          for (int r = 0; r < 4; ++r)
            tb[w * 32 + i * 16 + qd * 4 + r][j * 16 + l15] = f2bf(sigm(ag[i][j][r]) * av[i][j][r]);
      __syncthreads();                     // tb complete
      {
        ushort_t* dst = ab ? bT : aT;      // [cout][pos], 256B contiguous per row
        #pragma unroll
        for (int it = 0; it < 8; ++it) {
          int idx = tid + it * 256;        // 2048 x 16B chunks
          int row = idx >> 4, c16 = idx & 15;
          u32x4 v = *(const u32x4*)&tb[row][c16 * 8];
          *(u32x4*)&dst[(size_t)row * NPOS + pos0 + c16 * 8] = v;
        }
      }
      __syncthreads();                     // tb free for next mode
    }
  }
}

// ---------------- triangle einsum: per channel c, U_c = A_c · B_c^T (bf16) ----------------
// Swizzled LDS (conflict-free b128 frag reads), BK=32 double-buffered, 1 barrier/iter,
// tb epilogue aliased over the staging buffers (34KB total -> 4 blocks/CU).
__device__ __forceinline__ int uofs(int row, int c4) {
  return (row * 4 + (c4 ^ ((row >> 1) & 3))) * 8;   // ushort offset of swizzled 16B unit
}
__global__ void k_tri(const ushort_t* __restrict__ aT, const ushort_t* __restrict__ bT,
                      ushort_t* __restrict__ uT) {
  __shared__ u32x4 smem4[2176];           // 34816B: 2x(A8KB)+2x(B8KB) dbuf, aliased by tb
  ushort_t* lds = (ushort_t*)smem4;       // A buf b at ushort ofs b*4096; B at 8192+b*4096
  const int tid = threadIdx.x;
  const int lane = tid & 63, wid = tid >> 6;
  const int qd = lane >> 4, l15 = lane & 15;
  const int wm = wid & 1, wn = wid >> 1;
  const int c  = blockIdx.z;
  const int m0 = blockIdx.y * 128, n0 = blockIdx.x * 128;
  const ushort_t* A = aT + (size_t)c * NPOS;  // [512][512]
  const ushort_t* B = bT + (size_t)c * NPOS;
  const int sr = tid >> 2, c4 = tid & 3;

  u32x4 rA0, rA1, rB0, rB1;
  rA0 = *(const u32x4*)&A[(size_t)(m0 + sr)      * N_ + c4 * 8];
  rA1 = *(const u32x4*)&A[(size_t)(m0 + 64 + sr) * N_ + c4 * 8];
  rB0 = *(const u32x4*)&B[(size_t)(n0 + sr)      * N_ + c4 * 8];
  rB1 = *(const u32x4*)&B[(size_t)(n0 + 64 + sr) * N_ + c4 * 8];
  *(u32x4*)&lds[       uofs(sr,      c4)] = rA0;
  *(u32x4*)&lds[       uofs(sr + 64, c4)] = rA1;
  *(u32x4*)&lds[8192 + uofs(sr,      c4)] = rB0;
  *(u32x4*)&lds[8192 + uofs(sr + 64, c4)] = rB1;

  f32x4 acc[4][4] = {};
  for (int it = 1; it <= 16; ++it) {
    __syncthreads();                        // buf[curb] ready; buf[nxt] fully consumed
    const int curb = (it - 1) & 1, nxt = it & 1;
    if (it < 16) {                          // issue next-slab loads early (T14)
      const int ko = it * 32;
      rA0 = *(const u32x4*)&A[(size_t)(m0 + sr)      * N_ + ko + c4 * 8];
      rA1 = *(const u32x4*)&A[(size_t)(m0 + 64 + sr) * N_ + ko + c4 * 8];
      rB0 = *(const u32x4*)&B[(size_t)(n0 + sr)      * N_ + ko + c4 * 8];
      rB1 = *(const u32x4*)&B[(size_t)(n0 + 64 + sr) * N_ + ko + c4 * 8];
    }
    const ushort_t* la = lds + curb * 4096;
    const ushort_t* lb = lds + 8192 + curb * 4096;
    bf16x8 af[4], bfr[4];
    #pragma unroll
    for (int t = 0; t < 4; ++t) af[t]  = *(const bf16x8*)&la[uofs(wm * 64 + t * 16 + l15, qd)];
    #pragma unroll
    for (int t = 0; t < 4; ++t) bfr[t] = *(const bf16x8*)&lb[uofs(wn * 64 + t * 16 + l15, qd)];
    #pragma unroll
    for (int i = 0; i < 4; ++i)
      #pragma unroll
      for (int j = 0; j < 4; ++j)
        acc[i][j] = __builtin_amdgcn_mfma_f32_16x16x32_bf16(af[i], bfr[j], acc[i][j], 0, 0, 0);
    if (it < 16) {
      *(u32x4*)&lds[nxt * 4096 +        uofs(sr,      c4)] = rA0;
      *(u32x4*)&lds[nxt * 4096 +        uofs(sr + 64, c4)] = rA1;
      *(u32x4*)&lds[8192 + nxt * 4096 + uofs(sr,      c4)] = rB0;
      *(u32x4*)&lds[8192 + nxt * 4096 + uofs(sr + 64, c4)] = rB1;
    }
  }
  __syncthreads();                          // all frag reads done: smem reusable as tb
  ushort_t (*tb)[136] = (ushort_t(*)[136])smem4;
  #pragma unroll
  for (int i = 0; i < 4; ++i)
    #pragma unroll
    for (int j = 0; j < 4; ++j)
      #pragma unroll
      for (int r2 = 0; r2 < 4; ++r2)
        tb[wm * 64 + i * 16 + qd * 4 + r2][wn * 64 + j * 16 + l15] = f2bf(acc[i][j][r2]);
  __syncthreads();
  ushort_t* U = uT + (size_t)c * NPOS;
  #pragma unroll
  for (int it = 0; it < 8; ++it) {
    int idx = tid + it * 256;
    int row = idx >> 4, c16 = idx & 15;
    u32x4 v = *(const u32x4*)&tb[row][c16 * 8];
    *(u32x4*)&U[(size_t)(m0 + row) * N_ + n0 + c16 * 8] = v;
  }
}

// ---------------- fused epilogue: LN2(U)@w_out  *  sigmoid(LN1(pair)@w_gate) ----------------
// Gate recomputed from pair (exact f32 stats) -> second MFMA accumulator with identical
// D-fragment layout -> in-register gating. d_out is write-only (no RMW round-trip).
__global__ __launch_bounds__(256, 2)
void k_out(const ushort_t* __restrict__ uT, const ushort_t* __restrict__ wT,
           const float* __restrict__ pair,
           const float* __restrict__ g1, const float* __restrict__ b1,
           const float* __restrict__ g2, const float* __restrict__ b2,
           float* __restrict__ gout) {
  __shared__ ushort_t nu[128][136];   // LN2(U) tile [pos][c], padded (odd 16B stride: conflict-free)
  __shared__ ushort_t zn[128][136];   // LN1(pair) tile [pos][k]
  __shared__ float ps[2][128], pq[2][128];
  __shared__ float mu[128], rsd[128], gam[128], bet[128];
  const int tid = threadIdx.x;
  const int lane = tid & 63, wid = tid >> 6;
  const int qd = lane >> 4, l15 = lane & 15;
  const int pos0 = blockIdx.x * 128;
  const ushort_t* WgT = wT + 4 * CD * CD;   // w_gateT [cz][k]
  const ushort_t* WoT = wT + 5 * CD * CD;   // w_outT  [cz][c]

  if (tid < 128) { gam[tid] = g2[tid]; bet[tid] = b2[tid]; }

  // ---- phase 1: LN1(pair tile) -> zn ----
  {
    int r = tid >> 1, h = tid & 1;
    const float4* src = (const float4*)(pair + (size_t)(pos0 + r) * CD + h * 64);
    float s = 0.f, sq = 0.f;
    #pragma unroll
    for (int u = 0; u < 16; ++u) {
      float4 v = src[u];
      s  += (v.x + v.y) + (v.z + v.w);
      sq += (v.x*v.x + v.y*v.y) + (v.z*v.z + v.w*v.w);
    }
    ps[h][r] = s; pq[h][r] = sq;
  }
  __syncthreads();
  if (tid < 128) {
    float s = ps[0][tid] + ps[1][tid];
    float m = s * (1.0f / 128.0f);
    float v = (pq[0][tid] + pq[1][tid]) * (1.0f / 128.0f) - m * m;
    mu[tid] = m; rsd[tid] = rsqrtf(v + 1e-5f);
  }
  __syncthreads();
  {
    int r = tid >> 1, h = tid & 1;
    float m = mu[r], rs = rsd[r];
    const float4* src = (const float4*)(pair + (size_t)(pos0 + r) * CD + h * 64);
    const float4* gp = (const float4*)(g1 + h * 64);
    const float4* bp = (const float4*)(b1 + h * 64);
    #pragma unroll
    for (int u2 = 0; u2 < 8; ++u2) {
      float4 v0 = src[u2*2], v1 = src[u2*2+1];
      float4 ga = gp[u2*2], gb2 = gp[u2*2+1];
      float4 ba = bp[u2*2], bb2 = bp[u2*2+1];
      uint_t w0 = (uint_t)f2bf((v0.x-m)*rs*ga.x +ba.x ) | ((uint_t)f2bf((v0.y-m)*rs*ga.y +ba.y ) << 16);
      uint_t w1 = (uint_t)f2bf((v0.z-m)*rs*ga.z +ba.z ) | ((uint_t)f2bf((v0.w-m)*rs*ga.w +ba.w ) << 16);
      uint_t w2 = (uint_t)f2bf((v1.x-m)*rs*gb2.x+bb2.x) | ((uint_t)f2bf((v1.y-m)*rs*gb2.y+bb2.y) << 16);
      uint_t w3 = (uint_t)f2bf((v1.z-m)*rs*gb2.z+bb2.z) | ((uint_t)f2bf((v1.w-m)*rs*gb2.w+bb2.w) << 16);
      u32x4 pk = {w0, w1, w2, w3};
      *(u32x4*)&zn[r][h * 64 + u2 * 8] = pk;
    }
  }
  __syncthreads();

  // ---- phase 2: LN2 on U tile -> nu ----
  { // pass 1: load raw U tile (transposed into nu[pos][c]) + stats
    int p = tid & 127, h = tid >> 7;
    float s = 0.f, sq = 0.f;
    for (int cc = h * 64; cc < h * 64 + 64; ++cc) {
      ushort_t raw = uT[(size_t)cc * NPOS + pos0 + p];
      nu[p][cc] = raw;
      float v = bf2f(raw); s += v; sq += v * v;
    }
    ps[h][p] = s; pq[h][p] = sq;
  }
  __syncthreads();
  if (tid < 128) {
    float s = ps[0][tid] + ps[1][tid];
    float m = s * (1.0f / 128.0f);
    float v = (pq[0][tid] + pq[1][tid]) * (1.0f / 128.0f) - m * m;
    mu[tid] = m; rsd[tid] = rsqrtf(v + 1e-5f);
  }
  __syncthreads();
  { // pass 2: normalize in place
    int p = tid & 127, h = tid >> 7;
    float m = mu[p], rs = rsd[p];
    for (int cc = h * 64; cc < h * 64 + 64; ++cc)
      nu[p][cc] = f2bf((bf2f(nu[p][cc]) - m) * rs * gam[cc] + bet[cc]);
  }
  __syncthreads();

  // ---- phase 3: dual GEMM (out + gate, identical D layouts) + fused gating ----
  const int wm = wid & 1, wn = wid >> 1;
  f32x4 ao[4][4] = {}; f32x4 agt[4][4] = {};
  for (int kk = 0; kk < 4; ++kk) {
    bf16x8 afo[4], afg[4];
    #pragma unroll
    for (int i = 0; i < 4; ++i) {
      int wrow = (wm * 64 + i * 16 + l15) * CD + kk * 32 + qd * 8;
      afo[i] = *(const bf16x8*)(WoT + wrow);
      afg[i] = *(const bf16x8*)(WgT + wrow);
    }
    #pragma unroll
    for (int j = 0; j < 4; ++j) {
      bf16x8 bn = *(const bf16x8*)&nu[wn * 64 + j * 16 + l15][kk * 32 + qd * 8];
      bf16x8 bz = *(const bf16x8*)&zn[wn * 64 + j * 16 + l15][kk * 32 + qd * 8];
      #pragma unroll
      for (int i = 0; i < 4; ++i) {
        ao[i][j]  = __builtin_amdgcn_mfma_f32_16x16x32_bf16(afo[i], bn, ao[i][j],  0, 0, 0);
        agt[i][j] = __builtin_amdgcn_mfma_f32_16x16x32_bf16(afg[i], bz, agt[i][j], 0, 0, 0);
      }
    }
  }
  #pragma unroll
  for (int i = 0; i < 4; ++i) {
    int cz = wm * 64 + i * 16 + qd * 4;
    #pragma unroll
    for (int j = 0; j < 4; ++j) {
      int pos = pos0 + wn * 64 + j * 16 + l15;
      float4 pk;
      pk.x = sigm(agt[i][j][0]) * ao[i][j][0];
      pk.y = sigm(agt[i][j][1]) * ao[i][j][1];
      pk.z = sigm(agt[i][j][2]) * ao[i][j][2];
      pk.w = sigm(agt[i][j][3]) * ao[i][j][3];
      *(float4*)&gout[(size_t)pos * CD + cz] = pk;
    }
  }
}

extern "C" void kernel_launch(void* const* d_in, const int* in_sizes, int n_in,
                              void* d_out, int out_size, void* d_ws, size_t ws_size,
                              hipStream_t stream) {
  const float* pair = (const float*)d_in[0];
  const float* g1   = (const float*)d_in[1];
  const float* b1   = (const float*)d_in[2];
  const float* wga  = (const float*)d_in[3];
  const float* wgb  = (const float*)d_in[4];
  const float* wa   = (const float*)d_in[5];
  const float* wb   = (const float*)d_in[6];
  const float* g2   = (const float*)d_in[7];
  const float* b2   = (const float*)d_in[8];
  const float* wout = (const float*)d_in[9];
  const float* wg   = (const float*)d_in[10];

  char* ws = (char*)d_ws;
  ushort_t* z  = (ushort_t*)(ws);                 // 64MiB bf16; reused as uT after k_proj
  ushort_t* aT = (ushort_t*)(ws + 67108864);      // 64MiB bf16 [c][pos]
  ushort_t* bT = (ushort_t*)(ws + 134217728);     // 64MiB bf16 [c][pos]
  ushort_t* wT = (ushort_t*)(ws + 201326592);     // 6 * 32KB transposed bf16 weights
  ushort_t* uT = z;
  float*    gb = (float*)d_out;                   // final output (write-only)

  k_tw  <<<6, 256, 0, stream>>>(wga, wa, wgb, wb, wg, wout, wT);
  k_ln1 <<<NPOS / 16, 256, 0, stream>>>(pair, g1, b1, z);
  k_proj<<<512, 256, 0, stream>>>(z, wT, aT, bT);
  k_tri <<<dim3(4, 4, 128), 256, 0, stream>>>(aT, bT, uT);
  k_out <<<2048, 256, 0, stream>>>(uT, wT, pair, g1, b1, g2, b2, gb);
}

// Round 5
// 543.972 us; speedup vs baseline: 1.0055x; 1.0055x over previous
//
#include <hip/hip_runtime.h>

#define N_ 512
#define NPOS (N_*N_)   // 262144
#define CD 128         // C == CZ == 128

typedef unsigned short ushort_t;
typedef unsigned int   uint_t;
typedef __bf16 bf16_t;
typedef bf16_t  bf16x8 __attribute__((ext_vector_type(8)));
typedef float   f32x4  __attribute__((ext_vector_type(4)));
typedef unsigned short u16x4 __attribute__((ext_vector_type(4)));
typedef uint_t  u32x4 __attribute__((ext_vector_type(4)));

__device__ __forceinline__ float bf2f(ushort_t h) {
  union { uint_t u; float f; } v; v.u = ((uint_t)h) << 16; return v.f;
}
__device__ __forceinline__ float bf2f_lo(uint_t w) {
  union { uint_t u; float f; } v; v.u = w << 16; return v.f;
}
__device__ __forceinline__ float bf2f_hi(uint_t w) {
  union { uint_t u; float f; } v; v.u = w & 0xffff0000u; return v.f;
}
__device__ __forceinline__ ushort_t f2bf(float f) {
  union { float f; uint_t u; } v; v.f = f;
  uint_t u = v.u;
  return (ushort_t)((u + 0x7FFFu + ((u >> 16) & 1u)) >> 16);
}
__device__ __forceinline__ float sigm(float x) { return 1.0f / (1.0f + __expf(-x)); }

// ---------------- weight transposes (f32 -> bf16): wT[m][c][k] = W_m[k][c] ----------------
// Block 5 (w_out) folds ln2_gamma into the weight and emits
// K1[cz] = sum_c gam[c]*Wo[c][cz], K2[cz] = sum_c bet[c]*Wo[c][cz] (f32).
__global__ void k_tw(const float* s0, const float* s1, const float* s2,
                     const float* s3, const float* s4, const float* s5,
                     ushort_t* dst, const float* lg2, const float* lb2, float* K12) {
  const float* s;
  switch (blockIdx.x) {
    case 0: s = s0; break; case 1: s = s1; break; case 2: s = s2; break;
    case 3: s = s3; break; case 4: s = s4; break; default: s = s5; break;
  }
  ushort_t* d = dst + blockIdx.x * CD * CD;
  if (blockIdx.x == 5) {
    for (int idx = threadIdx.x; idx < CD * CD; idx += 256) {
      int cz = idx >> 7, ci = idx & 127;
      d[idx] = f2bf(s[ci * CD + cz] * lg2[ci]);      // gamma-folded WoT'
    }
    if (threadIdx.x < 128) {
      int cz = threadIdx.x;
      float k1 = 0.f, k2 = 0.f;
      for (int ci = 0; ci < 128; ++ci) {
        float w = s[ci * CD + cz];
        k1 += lg2[ci] * w; k2 += lb2[ci] * w;
      }
      K12[cz] = k1; K12[128 + cz] = k2;
    }
  } else {
    for (int idx = threadIdx.x; idx < CD * CD; idx += 256) {
      int c = idx >> 7, k = idx & 127;
      d[idx] = f2bf(s[k * CD + c]);
    }
  }
}

// ---------------- LN1 (f32 in, bf16 out): 16 lanes per row, f32x4 loads ----------------
__global__ void k_ln1(const float* __restrict__ x, const float* __restrict__ gma,
                      const float* __restrict__ bta, ushort_t* __restrict__ z) {
  const int tid  = threadIdx.x;
  const int l15  = tid & 15;
  const int row  = blockIdx.x * 16 + (tid >> 4);
  const float4* src = (const float4*)(x + (size_t)row * CD + l15 * 8);
  float4 v0 = src[0], v1 = src[1];
  float s = ((v0.x + v0.y) + (v0.z + v0.w)) + ((v1.x + v1.y) + (v1.z + v1.w));
  float q = ((v0.x*v0.x + v0.y*v0.y) + (v0.z*v0.z + v0.w*v0.w))
          + ((v1.x*v1.x + v1.y*v1.y) + (v1.z*v1.z + v1.w*v1.w));
  #pragma unroll
  for (int o = 1; o < 16; o <<= 1) { s += __shfl_xor(s, o, 64); q += __shfl_xor(q, o, 64); }
  float mu = s * (1.0f / 128.0f);
  float rs = rsqrtf(q * (1.0f / 128.0f) - mu * mu + 1e-5f);
  const float4* gp = (const float4*)(gma + l15 * 8);
  const float4* bp = (const float4*)(bta + l15 * 8);
  float4 g0 = gp[0], g1v = gp[1], b0 = bp[0], b1v = bp[1];
  uint_t w0 = (uint_t)f2bf((v0.x-mu)*rs*g0.x +b0.x ) | ((uint_t)f2bf((v0.y-mu)*rs*g0.y +b0.y ) << 16);
  uint_t w1 = (uint_t)f2bf((v0.z-mu)*rs*g0.z +b0.z ) | ((uint_t)f2bf((v0.w-mu)*rs*g0.w +b0.w ) << 16);
  uint_t w2 = (uint_t)f2bf((v1.x-mu)*rs*g1v.x+b1v.x) | ((uint_t)f2bf((v1.y-mu)*rs*g1v.y+b1v.y) << 16);
  uint_t w3 = (uint_t)f2bf((v1.z-mu)*rs*g1v.z+b1v.z) | ((uint_t)f2bf((v1.w-mu)*rs*g1v.w+b1v.w) << 16);
  u32x4 pk = {w0, w1, w2, w3};
  *(u32x4*)(z + (size_t)row * CD + l15 * 8) = pk;
}

// ---------------- projections a,b,g: weights persistent in registers, z pipelined ----------------
__global__ __launch_bounds__(256, 1)
void k_proj(const ushort_t* __restrict__ z, const ushort_t* __restrict__ wT,
            ushort_t* __restrict__ aT, ushort_t* __restrict__ bT,
            float* __restrict__ g) {
  __shared__ ushort_t zl[128 * 128];   // 32KB, XOR-swizzled 16B units
  __shared__ ushort_t tb[128][136];    // 34KB transpose buffer (272B rows)
  const int tid = threadIdx.x;
  const int lane = tid & 63, w = tid >> 6;
  const int qd = lane >> 4, l15 = lane & 15;

  // persistent weight fragments: wf[m][i][kk] row = 32w+i*16+l15, col = kk*32+qd*8
  bf16x8 wf[5][2][4];
  #pragma unroll
  for (int m = 0; m < 5; ++m)
    #pragma unroll
    for (int i = 0; i < 2; ++i)
      #pragma unroll
      for (int kk = 0; kk < 4; ++kk)
        wf[m][i][kk] = *(const bf16x8*)(wT + m * CD * CD + (w * 32 + i * 16 + l15) * CD + kk * 32 + qd * 8);

  const int TILES = 4;
  const int base = blockIdx.x * TILES;

  u32x4 st[8];
  { // prologue: prefetch tile 0 into registers
    const u32x4* src = (const u32x4*)(z + (size_t)base * 128 * CD);
    #pragma unroll
    for (int i = 0; i < 8; ++i) st[i] = src[tid + i * 256];
  }

  for (int t = 0; t < TILES; ++t) {
    const int pos0 = (base + t) * 128;
    __syncthreads();                       // prev tile's zl readers done
    { // staged regs -> swizzled zl
      u32x4* dst = (u32x4*)zl;
      #pragma unroll
      for (int i = 0; i < 8; ++i) {
        int u = tid + i * 256, row = u >> 4;
        dst[(u & ~15) | ((u & 15) ^ (row & 7))] = st[i];
      }
    }
    __syncthreads();                       // zl ready for all waves
    if (t + 1 < TILES) {                   // prefetch next tile (hidden under compute)
      const u32x4* src = (const u32x4*)(z + (size_t)(base + t + 1) * 128 * CD);
      #pragma unroll
      for (int i = 0; i < 8; ++i) st[i] = src[tid + i * 256];
    }

    #pragma unroll
    for (int ab = 0; ab < 2; ++ab) {
      f32x4 ag[2][8] = {}; f32x4 av[2][8] = {};
      #pragma unroll
      for (int kk = 0; kk < 4; ++kk) {
        bf16x8 zf[8];
        #pragma unroll
        for (int j = 0; j < 8; ++j) {
          int row = j * 16 + l15, kq = kk * 4 + qd;
          zf[j] = ((const bf16x8*)zl)[(row << 4) | (kq ^ (row & 7))];
        }
        #pragma unroll
        for (int j = 0; j < 8; ++j)
          #pragma unroll
          for (int i = 0; i < 2; ++i) {
            ag[i][j] = __builtin_amdgcn_mfma_f32_16x16x32_bf16(wf[ab * 2][i][kk],     zf[j], ag[i][j], 0, 0, 0);
            av[i][j] = __builtin_amdgcn_mfma_f32_16x16x32_bf16(wf[ab * 2 + 1][i][kk], zf[j], av[i][j], 0, 0, 0);
          }
      }
      // epilogue: gate, transpose via tb, full-line stores
      #pragma unroll
      for (int i = 0; i < 2; ++i)
        #pragma unroll
        for (int j = 0; j < 8; ++j)
          #pragma unroll
          for (int r = 0; r < 4; ++r)
            tb[w * 32 + i * 16 + qd * 4 + r][j * 16 + l15] = f2bf(sigm(ag[i][j][r]) * av[i][j][r]);
      __syncthreads();                     // tb complete
      {
        ushort_t* dst = ab ? bT : aT;      // [cout][pos], 256B contiguous per row
        #pragma unroll
        for (int it = 0; it < 8; ++it) {
          int idx = tid + it * 256;        // 2048 x 16B chunks
          int row = idx >> 4, c16 = idx & 15;
          u32x4 v = *(const u32x4*)&tb[row][c16 * 8];
          *(u32x4*)&dst[(size_t)row * NPOS + pos0 + c16 * 8] = v;
        }
      }
      __syncthreads();                     // tb free for next mode
    }

    // ---- mode g: g = sigmoid(z @ wgate), f32 [pos][cz] direct stores ----
    {
      f32x4 acc[2][8] = {};
      #pragma unroll
      for (int kk = 0; kk < 4; ++kk) {
        bf16x8 zf[8];
        #pragma unroll
        for (int j = 0; j < 8; ++j) {
          int row = j * 16 + l15, kq = kk * 4 + qd;
          zf[j] = ((const bf16x8*)zl)[(row << 4) | (kq ^ (row & 7))];
        }
        #pragma unroll
        for (int j = 0; j < 8; ++j)
          #pragma unroll
          for (int i = 0; i < 2; ++i)
            acc[i][j] = __builtin_amdgcn_mfma_f32_16x16x32_bf16(wf[4][i][kk], zf[j], acc[i][j], 0, 0, 0);
      }
      #pragma unroll
      for (int i = 0; i < 2; ++i) {
        int cz = w * 32 + i * 16 + qd * 4;
        #pragma unroll
        for (int j = 0; j < 8; ++j) {
          int pos = pos0 + j * 16 + l15;
          float4 pk;
          pk.x = sigm(acc[i][j][0]); pk.y = sigm(acc[i][j][1]);
          pk.z = sigm(acc[i][j][2]); pk.w = sigm(acc[i][j][3]);
          *(float4*)&g[(size_t)pos * CD + cz] = pk;
        }
      }
    }
  }
}

// ---------------- triangle einsum: per channel c, U_c = A_c · B_c^T (bf16) ----------------
__device__ __forceinline__ int uofs(int row, int c4) {
  return (row * 4 + (c4 ^ ((row >> 1) & 3))) * 8;   // ushort offset of swizzled 16B unit
}
__global__ void k_tri(const ushort_t* __restrict__ aT, const ushort_t* __restrict__ bT,
                      ushort_t* __restrict__ uT) {
  __shared__ u32x4 smem4[2176];           // 34816B: 2x(A8KB)+2x(B8KB) dbuf, aliased by tb
  ushort_t* lds = (ushort_t*)smem4;       // A buf b at ushort ofs b*4096; B at 8192+b*4096
  const int tid = threadIdx.x;
  const int lane = tid & 63, wid = tid >> 6;
  const int qd = lane >> 4, l15 = lane & 15;
  const int wm = wid & 1, wn = wid >> 1;
  const int c  = blockIdx.z;
  const int m0 = blockIdx.y * 128, n0 = blockIdx.x * 128;
  const ushort_t* A = aT + (size_t)c * NPOS;  // [512][512]
  const ushort_t* B = bT + (size_t)c * NPOS;
  const int sr = tid >> 2, c4 = tid & 3;

  u32x4 rA0, rA1, rB0, rB1;
  rA0 = *(const u32x4*)&A[(size_t)(m0 + sr)      * N_ + c4 * 8];
  rA1 = *(const u32x4*)&A[(size_t)(m0 + 64 + sr) * N_ + c4 * 8];
  rB0 = *(const u32x4*)&B[(size_t)(n0 + sr)      * N_ + c4 * 8];
  rB1 = *(const u32x4*)&B[(size_t)(n0 + 64 + sr) * N_ + c4 * 8];
  *(u32x4*)&lds[       uofs(sr,      c4)] = rA0;
  *(u32x4*)&lds[       uofs(sr + 64, c4)] = rA1;
  *(u32x4*)&lds[8192 + uofs(sr,      c4)] = rB0;
  *(u32x4*)&lds[8192 + uofs(sr + 64, c4)] = rB1;

  f32x4 acc[4][4] = {};
  for (int it = 1; it <= 16; ++it) {
    __syncthreads();                        // buf[curb] ready; buf[nxt] fully consumed
    const int curb = (it - 1) & 1, nxt = it & 1;
    if (it < 16) {                          // issue next-slab loads early (T14)
      const int ko = it * 32;
      rA0 = *(const u32x4*)&A[(size_t)(m0 + sr)      * N_ + ko + c4 * 8];
      rA1 = *(const u32x4*)&A[(size_t)(m0 + 64 + sr) * N_ + ko + c4 * 8];
      rB0 = *(const u32x4*)&B[(size_t)(n0 + sr)      * N_ + ko + c4 * 8];
      rB1 = *(const u32x4*)&B[(size_t)(n0 + 64 + sr) * N_ + ko + c4 * 8];
    }
    const ushort_t* la = lds + curb * 4096;
    const ushort_t* lb = lds + 8192 + curb * 4096;
    bf16x8 af[4], bfr[4];
    #pragma unroll
    for (int t = 0; t < 4; ++t) af[t]  = *(const bf16x8*)&la[uofs(wm * 64 + t * 16 + l15, qd)];
    #pragma unroll
    for (int t = 0; t < 4; ++t) bfr[t] = *(const bf16x8*)&lb[uofs(wn * 64 + t * 16 + l15, qd)];
    #pragma unroll
    for (int i = 0; i < 4; ++i)
      #pragma unroll
      for (int j = 0; j < 4; ++j)
        acc[i][j] = __builtin_amdgcn_mfma_f32_16x16x32_bf16(af[i], bfr[j], acc[i][j], 0, 0, 0);
    if (it < 16) {
      *(u32x4*)&lds[nxt * 4096 +        uofs(sr,      c4)] = rA0;
      *(u32x4*)&lds[nxt * 4096 +        uofs(sr + 64, c4)] = rA1;
      *(u32x4*)&lds[8192 + nxt * 4096 + uofs(sr,      c4)] = rB0;
      *(u32x4*)&lds[8192 + nxt * 4096 + uofs(sr + 64, c4)] = rB1;
    }
  }
  __syncthreads();                          // all frag reads done: smem reusable as tb
  ushort_t (*tb)[136] = (ushort_t(*)[136])smem4;
  #pragma unroll
  for (int i = 0; i < 4; ++i)
    #pragma unroll
    for (int j = 0; j < 4; ++j)
      #pragma unroll
      for (int r2 = 0; r2 < 4; ++r2)
        tb[wm * 64 + i * 16 + qd * 4 + r2][wn * 64 + j * 16 + l15] = f2bf(acc[i][j][r2]);
  __syncthreads();
  ushort_t* U = uT + (size_t)c * NPOS;
  #pragma unroll
  for (int it = 0; it < 8; ++it) {
    int idx = tid + it * 256;
    int row = idx >> 4, c16 = idx & 15;
    u32x4 v = *(const u32x4*)&tb[row][c16 * 8];
    *(u32x4*)&U[(size_t)(m0 + row) * N_ + n0 + c16 * 8] = v;
  }
}

// ---------------- LN2-folded epilogue: out = g * (rs*(Uraw@WoT' - mu*K1) + K2) ----------------
// Vectorized register-staged U load + in-register 8x8 transpose -> swizzled [pos][c] LDS tile.
// Swizzle: unit = row*17 + (c16 ^ ((row>>3)&7)) — odd stride spreads GEMM reads (row low bits),
// XOR of row bits 3-5 spreads transpose writes (rows stride-8 apart). Both ~2-way = free.
__device__ __forceinline__ int nuofs(int row, int c16) {
  return (row * 17 + (c16 ^ ((row >> 3) & 7))) * 8;   // ushort offset of 16B unit
}
__global__ __launch_bounds__(256, 2)
void k_out(const ushort_t* __restrict__ uT, const ushort_t* __restrict__ wT,
           const float* __restrict__ K12, float* gout) {
  __shared__ ushort_t nu[128 * 17 * 8];    // 34816B swizzled raw-U^T tile
  __shared__ float red[2][4][16][8];       // partial sums [sq][wave][pch][r], 4KB
  __shared__ float muL[128], rsL[128], K1s[128], K2s[128];
  const int tid = threadIdx.x;
  const int lane = tid & 63, wid = tid >> 6;
  const int qd = lane >> 4, l15 = lane & 15;
  const int pos0 = blockIdx.x * 128;
  const int pch = tid & 15, cbase = tid >> 4;   // pos-chunk 0..15, c-group 0..15
  const ushort_t* WoT = wT + 5 * CD * CD;       // gamma-folded w_outT' [cz][c]

  if (tid < 128) { K1s[tid] = K12[tid]; K2s[tid] = K12[128 + tid]; }

  // ---- load 8 coalesced 16B chunks: c = cbase*8+i, pos = pos0 + pch*8 .. +8 ----
  uint_t c8[8][4];
  #pragma unroll
  for (int i = 0; i < 8; ++i) {
    u32x4 v = *(const u32x4*)&uT[(size_t)(cbase * 8 + i) * NPOS + pos0 + pch * 8];
    c8[i][0] = v[0]; c8[i][1] = v[1]; c8[i][2] = v[2]; c8[i][3] = v[3];
  }

  // ---- stats: per-pos partial sums over this thread's 8 channels ----
  float s8[8] = {}, q8[8] = {};
  #pragma unroll
  for (int i = 0; i < 8; ++i)
    #pragma unroll
    for (int wd = 0; wd < 4; ++wd) {
      float vlo = bf2f_lo(c8[i][wd]), vhi = bf2f_hi(c8[i][wd]);
      s8[wd * 2]     += vlo; q8[wd * 2]     += vlo * vlo;
      s8[wd * 2 + 1] += vhi; q8[wd * 2 + 1] += vhi * vhi;
    }
  #pragma unroll
  for (int r = 0; r < 8; ++r) {
    s8[r] += __shfl_xor(s8[r], 16, 64); q8[r] += __shfl_xor(q8[r], 16, 64);
    s8[r] += __shfl_xor(s8[r], 32, 64); q8[r] += __shfl_xor(q8[r], 32, 64);
  }
  if (lane < 16) {
    #pragma unroll
    for (int r = 0; r < 8; ++r) { red[0][wid][lane][r] = s8[r]; red[1][wid][lane][r] = q8[r]; }
  }

  // ---- in-register 8x8 bf16 transpose -> swizzled nu[pos][c] (b128 writes) ----
  #pragma unroll
  for (int r = 0; r < 8; ++r) {
    u32x4 t;
    #pragma unroll
    for (int k = 0; k < 4; ++k) {
      uint_t a = c8[2 * k][r >> 1], b = c8[2 * k + 1][r >> 1];
      uint_t sh = (r & 1) * 16;
      t[k] = ((a >> sh) & 0xffffu) | (((b >> sh) & 0xffffu) << 16);
    }
    *(u32x4*)&nu[nuofs(pch * 8 + r, cbase)] = t;
  }
  __syncthreads();

  // ---- finalize per-pos stats ----
  if (tid < 128) {
    int p2 = tid >> 3, r2 = tid & 7;
    float s = red[0][0][p2][r2] + red[0][1][p2][r2] + red[0][2][p2][r2] + red[0][3][p2][r2];
    float q = red[1][0][p2][r2] + red[1][1][p2][r2] + red[1][2][p2][r2] + red[1][3][p2][r2];
    float m = s * (1.0f / 128.0f);
    float v = q * (1.0f / 128.0f) - m * m;
    muL[tid] = m; rsL[tid] = rsqrtf(v + 1e-5f);
  }
  __syncthreads();

  // ---- GEMM on raw U: D[cz][pos] = WoT'[cz][c] · nu[pos][c]^T ----
  const int wm = wid & 1, wn = wid >> 1;
  f32x4 acc[4][4] = {};
  for (int kk = 0; kk < 4; ++kk) {
    bf16x8 afo[4];
    #pragma unroll
    for (int i = 0; i < 4; ++i)
      afo[i] = *(const bf16x8*)(WoT + (wm * 64 + i * 16 + l15) * CD + kk * 32 + qd * 8);
    #pragma unroll
    for (int j = 0; j < 4; ++j) {
      bf16x8 bn = *(const bf16x8*)&nu[nuofs(wn * 64 + j * 16 + l15, kk * 4 + qd)];
      #pragma unroll
      for (int i = 0; i < 4; ++i)
        acc[i][j] = __builtin_amdgcn_mfma_f32_16x16x32_bf16(afo[i], bn, acc[i][j], 0, 0, 0);
    }
  }

  // ---- epilogue: LN2 affine fix + gate (read-then-overwrite, same pointer) ----
  #pragma unroll
  for (int i = 0; i < 4; ++i) {
    int cz = wm * 64 + i * 16 + qd * 4;
    float4 k1 = *(const float4*)&K1s[cz];
    float4 k2 = *(const float4*)&K2s[cz];
    #pragma unroll
    for (int j = 0; j < 4; ++j) {
      int pl = wn * 64 + j * 16 + l15;        // pos within tile
      float m = muL[pl], rr = rsL[pl];
      int pos = pos0 + pl;
      float4 gv = *(const float4*)&gout[(size_t)pos * CD + cz];   // gate (read first)
      float4 pk;
      pk.x = gv.x * (rr * (acc[i][j][0] - m * k1.x) + k2.x);
      pk.y = gv.y * (rr * (acc[i][j][1] - m * k1.y) + k2.y);
      pk.z = gv.z * (rr * (acc[i][j][2] - m * k1.z) + k2.z);
      pk.w = gv.w * (rr * (acc[i][j][3] - m * k1.w) + k2.w);
      *(float4*)&gout[(size_t)pos * CD + cz] = pk;                // overwrite with output
    }
  }
}

extern "C" void kernel_launch(void* const* d_in, const int* in_sizes, int n_in,
                              void* d_out, int out_size, void* d_ws, size_t ws_size,
                              hipStream_t stream) {
  const float* pair = (const float*)d_in[0];
  const float* g1   = (const float*)d_in[1];
  const float* b1   = (const float*)d_in[2];
  const float* wga  = (const float*)d_in[3];
  const float* wgb  = (const float*)d_in[4];
  const float* wa   = (const float*)d_in[5];
  const float* wb   = (const float*)d_in[6];
  const float* g2   = (const float*)d_in[7];
  const float* b2   = (const float*)d_in[8];
  const float* wout = (const float*)d_in[9];
  const float* wg   = (const float*)d_in[10];

  char* ws = (char*)d_ws;
  ushort_t* z   = (ushort_t*)(ws);                 // 64MiB bf16; reused as uT after k_proj
  ushort_t* aT  = (ushort_t*)(ws + 67108864);      // 64MiB bf16 [c][pos]
  ushort_t* bT  = (ushort_t*)(ws + 134217728);     // 64MiB bf16 [c][pos]
  ushort_t* wT  = (ushort_t*)(ws + 201326592);     // 6 * 32KB transposed bf16 weights
  float*    K12 = (float*)(ws + 201326592 + 196608); // 2*128 f32 (K1, K2)
  ushort_t* uT = z;
  float*    gb = (float*)d_out;                    // f32 gate staged in d_out, then final output

  k_tw  <<<6, 256, 0, stream>>>(wga, wa, wgb, wb, wg, wout, wT, g2, b2, K12);
  k_ln1 <<<NPOS / 16, 256, 0, stream>>>(pair, g1, b1, z);
  k_proj<<<512, 256, 0, stream>>>(z, wT, aT, bT, gb);
  k_tri <<<dim3(4, 4, 128), 256, 0, stream>>>(aT, bT, uT);
  k_out <<<2048, 256, 0, stream>>>(uT, wT, K12, gb);
}